// Round 1
// baseline (262.173 us; speedup 1.0000x reference)
//
#include <hip/hip_runtime.h>
#include <math.h>

#define HW 65536
#define DD 160
#define NB 2
#define SUB 40

#define SSIM_C1 1e-4f
#define SSIM_C2 9e-4f

struct Gw { float g[7]; };

static inline int imin(int a, int b) { return a < b ? a : b; }
static inline int imax(int a, int b) { return a > b ? a : b; }

// K1: 2D separable conv (W then H) of the 5 fields for one (n,d) slice tile.
// grid (8,8,nsl), block 256. Tile 32x32 outputs, halo 3 -> 38x38 staged.
__global__ __launch_bounds__(256) void k1_conv2d(
    const float* __restrict__ img1, const float* __restrict__ img2,
    float* __restrict__ interm, int s_lo, Gw gw)
{
    __shared__ float sx[38][40];
    __shared__ float sy[38][40];
    __shared__ float b1[5][38][33];

    const int tid = threadIdx.x;
    const int d  = s_lo + blockIdx.z;
    const int h0 = blockIdx.y * 32;
    const int w0 = blockIdx.x * 32;
    const float* p1 = img1 + (size_t)d * HW;
    const float* p2 = img2 + (size_t)d * HW;

    // stage with zero padding
    for (int idx = tid; idx < 38 * 38; idx += 256) {
        int hh = idx / 38;
        int ww = idx - hh * 38;
        int gh = h0 - 3 + hh;
        int gwp = w0 - 3 + ww;
        bool ok = ((unsigned)gh < 256u) && ((unsigned)gwp < 256u);
        int off = gh * 256 + gwp;
        float vx = 0.f, vy = 0.f;
        if (ok) { vx = p1[off]; vy = p2[off]; }
        sx[hh][ww] = vx;
        sy[hh][ww] = vy;
    }
    __syncthreads();

    // W-pass: 38 rows x 8 runs-of-4 = 304 tasks
    for (int task = tid; task < 38 * 8; task += 256) {
        int hh = task >> 3;
        int wb = (task & 7) * 4;
        float xv[10], yv[10], pxx[10], pyy[10], pxy[10];
#pragma unroll
        for (int i = 0; i < 10; ++i) { xv[i] = sx[hh][wb + i]; yv[i] = sy[hh][wb + i]; }
#pragma unroll
        for (int i = 0; i < 10; ++i) { pxx[i] = xv[i] * xv[i]; pyy[i] = yv[i] * yv[i]; pxy[i] = xv[i] * yv[i]; }
        float a[4][5];
#pragma unroll
        for (int o = 0; o < 4; ++o)
#pragma unroll
            for (int f = 0; f < 5; ++f) a[o][f] = 0.f;
#pragma unroll
        for (int k = 0; k < 7; ++k) {
            float gk = gw.g[k];
#pragma unroll
            for (int o = 0; o < 4; ++o) {
                int i = o + k;
                a[o][0] += gk * xv[i];
                a[o][1] += gk * yv[i];
                a[o][2] += gk * pxx[i];
                a[o][3] += gk * pyy[i];
                a[o][4] += gk * pxy[i];
            }
        }
#pragma unroll
        for (int f = 0; f < 5; ++f)
#pragma unroll
            for (int o = 0; o < 4; ++o) b1[f][hh][wb + o] = a[o][f];
    }
    __syncthreads();

    // H-pass: 8 h-runs-of-4 x 32 w = 256 tasks, then store to global intermediate
    {
        int w  = tid & 31;
        int hb = (tid >> 5) * 4;
        float a[4][5];
#pragma unroll
        for (int o = 0; o < 4; ++o)
#pragma unroll
            for (int f = 0; f < 5; ++f) a[o][f] = 0.f;
#pragma unroll
        for (int f = 0; f < 5; ++f) {
            float v[10];
#pragma unroll
            for (int i = 0; i < 10; ++i) v[i] = b1[f][hb + i][w];
#pragma unroll
            for (int k = 0; k < 7; ++k) {
                float gk = gw.g[k];
#pragma unroll
                for (int o = 0; o < 4; ++o) a[o][f] += gk * v[o + k];
            }
        }
#pragma unroll
        for (int f = 0; f < 5; ++f)
#pragma unroll
            for (int o = 0; o < 4; ++o)
                interm[((size_t)blockIdx.z * 5 + f) * HW + (size_t)(h0 + hb + o) * 256 + (w0 + w)] = a[o][f];
    }
}

// K2: D-direction conv via register ring + SSIM + deterministic block reduce.
// grid (8,16,nz), block 512. Each thread owns one (h,w) column.
__global__ __launch_bounds__(512) void k2_dconv(
    const float* __restrict__ interm, int s_lo, int s_hi, int c0, int c1,
    Gw gw, float* __restrict__ partials, int pbase)
{
    const int tid = threadIdx.x;
    const int w = (blockIdx.x * 32) + (tid & 31);
    const int h = (blockIdx.y * 16) + (tid >> 5);
    const int o0 = c0 + blockIdx.z * SUB;
    const int o1 = (c1 < o0 + SUB) ? c1 : (o0 + SUB);
    const int subL = o1 - o0;
    const int s_need_hi = (s_hi < o1 + 3) ? s_hi : (o1 + 3);
    const int hw = h * 256 + w;

    float ring[7][5] = {};
    float lsum = 0.f;
    const int G = (subL + 12) / 7;
    for (int t = 0; t < G; ++t) {
#pragma unroll
        for (int p = 0; p < 7; ++p) {
            int r = 7 * t + p;
            int s = o0 - 3 + r;
            if (s >= s_lo && s < s_need_hi) {
                const float* base = interm + (size_t)(s - s_lo) * 5 * HW + hw;
#pragma unroll
                for (int f = 0; f < 5; ++f) ring[p][f] = base[(size_t)f * HW];
            } else {
#pragma unroll
                for (int f = 0; f < 5; ++f) ring[p][f] = 0.f;
            }
            int m = r - 6;
            if (m >= 0 && m < subL) {
                float c[5] = {0.f, 0.f, 0.f, 0.f, 0.f};
#pragma unroll
                for (int k = 0; k < 7; ++k) {
                    float gk = gw.g[k];
#pragma unroll
                    for (int f = 0; f < 5; ++f) c[f] += gk * ring[(p + 1 + k) % 7][f];
                }
                float mu1 = c[0], mu2 = c[1];
                float mu1s = mu1 * mu1, mu2s = mu2 * mu2, m12 = mu1 * mu2;
                float s1 = c[2] - mu1s, s2 = c[3] - mu2s, s12 = c[4] - m12;
                float num = (2.f * m12 + SSIM_C1) * (2.f * s12 + SSIM_C2);
                float den = (mu1s + mu2s + SSIM_C1) * (s1 + s2 + SSIM_C2);
                lsum += num / den;
            }
        }
    }

    __shared__ float red[512];
    red[tid] = lsum;
    __syncthreads();
    for (int off = 256; off > 0; off >>= 1) {
        if (tid < off) red[tid] += red[tid + off];
        __syncthreads();
    }
    if (tid == 0)
        partials[pbase + ((blockIdx.z * gridDim.y + blockIdx.y) * gridDim.x + blockIdx.x)] = red[0];
}

__global__ __launch_bounds__(256) void k_final(
    const float* __restrict__ partials, int n, float scale, float* __restrict__ out)
{
    __shared__ float red[256];
    float s = 0.f;
    for (int i = threadIdx.x; i < n; i += 256) s += partials[i];
    red[threadIdx.x] = s;
    __syncthreads();
    for (int off = 128; off > 0; off >>= 1) {
        if (threadIdx.x < off) red[threadIdx.x] += red[threadIdx.x + off];
        __syncthreads();
    }
    if (threadIdx.x == 0) out[0] = red[0] * scale;
}

extern "C" void kernel_launch(void* const* d_in, const int* in_sizes, int n_in,
                              void* d_out, int out_size, void* d_ws, size_t ws_size,
                              hipStream_t stream)
{
    const float* img1 = (const float*)d_in[0];
    const float* img2 = (const float*)d_in[1];
    float* out = (float*)d_out;
    float* interm = (float*)d_ws;

    Gw gw;
    {
        double gs[7], sum = 0.0;
        for (int i = 0; i < 7; ++i) { double x = i - 3; gs[i] = exp(-x * x / 4.5); sum += gs[i]; }
        for (int i = 0; i < 7; ++i) gw.g[i] = (float)(gs[i] / sum);
    }

    // partials region at the tail of the workspace (256 KB)
    size_t poff = (ws_size > (size_t)(1 << 20)) ? ((ws_size - 262144) & ~(size_t)255) : 0;
    float* partials = (float*)((char*)d_ws + poff);
    long cap = (long)(poff / ((size_t)5 * HW * 4));   // intermediate slice capacity
    int chunk = (cap > 166) ? 160 : (int)(cap - 6);
    if (chunk < 1) chunk = 1;
    if (chunk > 160) chunk = 160;

    int pbase = 0;
    for (int n = 0; n < NB; ++n) {
        for (int c0 = 0; c0 < DD; c0 += chunk) {
            int c1 = imin(DD, c0 + chunk);
            int slo = imax(0, c0 - 3);
            int shi = imin(DD, c1 + 3);
            int nsl = shi - slo;
            dim3 g1(8, 8, nsl);
            k1_conv2d<<<g1, dim3(256), 0, stream>>>(
                img1 + (size_t)n * DD * HW, img2 + (size_t)n * DD * HW, interm, slo, gw);
            int nz = (c1 - c0 + SUB - 1) / SUB;
            dim3 g2(8, 16, nz);
            k2_dconv<<<g2, dim3(512), 0, stream>>>(
                interm, slo, shi, c0, c1, gw, partials, pbase);
            pbase += 8 * 16 * nz;
        }
    }
    k_final<<<dim3(1), dim3(256), 0, stream>>>(
        partials, pbase, (float)(1.0 / 20971520.0), out);
}

// Round 2
// 186.493 us; speedup vs baseline: 1.4058x; 1.4058x over previous
//
#include <hip/hip_runtime.h>
#include <math.h>

#define HW 65536
#define DD 160
#define NB 2
#define DCH 80
#define NSL (DCH + 6)   // 86 slices per chunk incl. halo

#define SSIM_C1 1e-4f
#define SSIM_C2 9e-4f

struct Gw { float g[7]; };

// Fused SSIM3D: per block = one 32x32 (h,w) tile marching over an 80-slice D-chunk.
// Per slice: stage inputs (prefetched), separable W->H conv of 5 fields,
// insert into 7-deep register ring, D-conv + SSIM when ring full.
__global__ __launch_bounds__(512) void k_fused(
    const float* __restrict__ img1, const float* __restrict__ img2,
    Gw gw, float* __restrict__ partials)
{
    __shared__ float sx[38][41];
    __shared__ float sy[38][41];
    __shared__ float b1[5][38][33];
    __shared__ float red[512];

    const int tid = threadIdx.x;
    const int n  = blockIdx.z >> 1;
    const int o0 = (blockIdx.z & 1) * DCH;
    const int h0 = blockIdx.y * 32;
    const int w0 = blockIdx.x * 32;
    const float* i1 = img1 + (size_t)n * DD * HW;
    const float* i2 = img2 + (size_t)n * DD * HW;

    // staging per-thread constants (3 rounds x 512 threads cover 38x38=1444 px)
    int goff[3], loff[3];
    bool ok[3], wr[3];
#pragma unroll
    for (int q = 0; q < 3; ++q) {
        int idx = tid + 512 * q;
        int hh = idx / 38;
        int ww = idx - 38 * hh;
        int gh = h0 - 3 + hh;
        int gw2 = w0 - 3 + ww;
        wr[q] = (idx < 1444);
        ok[q] = wr[q] && ((unsigned)gh < 256u) && ((unsigned)gw2 < 256u);
        goff[q] = gh * 256 + gw2;
        loff[q] = hh * 41 + ww;
    }

    const int wcol = tid & 31;
    const int hb = (tid >> 5) * 2;   // 2 output rows per thread

    float ring[2][5][7] = {};
    float lsum = 0.f;

    float* sxf = &sx[0][0];
    float* syf = &sy[0][0];

    // prologue: stage s0 = o0-3 if it's a real slice
    {
        int s0 = o0 - 3;
        if (s0 >= 0) {
            const float* p1 = i1 + (size_t)s0 * HW;
            const float* p2 = i2 + (size_t)s0 * HW;
#pragma unroll
            for (int q = 0; q < 3; ++q) {
                float vx = ok[q] ? p1[goff[q]] : 0.f;
                float vy = ok[q] ? p2[goff[q]] : 0.f;
                if (wr[q]) { sxf[loff[q]] = vx; syf[loff[q]] = vy; }
            }
        }
        __syncthreads();
    }

    for (int t = 0; t < 13; ++t) {
#pragma unroll
        for (int p = 0; p < 7; ++p) {
            const int r = 7 * t + p;
            if (r < NSL) {
                const int s = o0 - 3 + r;
                const bool curv = (s >= 0 && s < DD);
                const int sn = s + 1;
                const bool nxtv = (r + 1 < NSL) && (sn >= 0) && (sn < DD);

                // 1) issue next slice's global loads early (latency hides under W-pass)
                float pfx[3], pfy[3];
                if (nxtv) {
                    const float* p1 = i1 + (size_t)sn * HW;
                    const float* p2 = i2 + (size_t)sn * HW;
#pragma unroll
                    for (int q = 0; q < 3; ++q) {
                        pfx[q] = ok[q] ? p1[goff[q]] : 0.f;
                        pfy[q] = ok[q] ? p2[goff[q]] : 0.f;
                    }
                }

                // 2) W-pass: 38 rows x 8 runs-of-4 = 304 tasks
                if (curv && tid < 304) {
                    const int hh = tid >> 3;
                    const int wb = (tid & 7) * 4;
                    float xv[10], yv[10], pxx[10], pyy[10], pxy[10];
#pragma unroll
                    for (int i = 0; i < 10; ++i) { xv[i] = sx[hh][wb + i]; yv[i] = sy[hh][wb + i]; }
#pragma unroll
                    for (int i = 0; i < 10; ++i) {
                        pxx[i] = xv[i] * xv[i]; pyy[i] = yv[i] * yv[i]; pxy[i] = xv[i] * yv[i];
                    }
                    float a[4][5] = {};
#pragma unroll
                    for (int k = 0; k < 7; ++k) {
                        const float gk = gw.g[k];
#pragma unroll
                        for (int o = 0; o < 4; ++o) {
                            const int i = o + k;
                            a[o][0] += gk * xv[i];
                            a[o][1] += gk * yv[i];
                            a[o][2] += gk * pxx[i];
                            a[o][3] += gk * pyy[i];
                            a[o][4] += gk * pxy[i];
                        }
                    }
#pragma unroll
                    for (int f = 0; f < 5; ++f)
#pragma unroll
                        for (int o = 0; o < 4; ++o) b1[f][hh][wb + o] = a[o][f];
                }
                __syncthreads();

                // 3) write prefetched next slice into sx/sy (reads of slice s are done)
                if (nxtv) {
#pragma unroll
                    for (int q = 0; q < 3; ++q)
                        if (wr[q]) { sxf[loff[q]] = pfx[q]; syf[loff[q]] = pfy[q]; }
                }

                // 4) H-pass -> ring insert at phase p
                if (curv) {
#pragma unroll
                    for (int f = 0; f < 5; ++f) {
                        float v[8];
#pragma unroll
                        for (int i = 0; i < 8; ++i) v[i] = b1[f][hb + i][wcol];
#pragma unroll
                        for (int o = 0; o < 2; ++o) {
                            float acc = 0.f;
#pragma unroll
                            for (int k = 0; k < 7; ++k) acc += gw.g[k] * v[o + k];
                            ring[o][f][p] = acc;
                        }
                    }
                } else {
#pragma unroll
                    for (int o = 0; o < 2; ++o)
#pragma unroll
                        for (int f = 0; f < 5; ++f) ring[o][f][p] = 0.f;
                }

                // 5) D-conv + SSIM for output slice r-6
                if (r >= 6) {
#pragma unroll
                    for (int o = 0; o < 2; ++o) {
                        float c0 = 0.f, c1 = 0.f, c2 = 0.f, c3 = 0.f, c4 = 0.f;
#pragma unroll
                        for (int k = 0; k < 7; ++k) {
                            const float gk = gw.g[k];
                            const int pp = (p + 1 + k) % 7;
                            c0 += gk * ring[o][0][pp];
                            c1 += gk * ring[o][1][pp];
                            c2 += gk * ring[o][2][pp];
                            c3 += gk * ring[o][3][pp];
                            c4 += gk * ring[o][4][pp];
                        }
                        const float mu1 = c0, mu2 = c1;
                        const float mu1s = mu1 * mu1, mu2s = mu2 * mu2, m12 = mu1 * mu2;
                        const float s1 = c2 - mu1s, s2 = c3 - mu2s, s12 = c4 - m12;
                        const float num = (2.f * m12 + SSIM_C1) * (2.f * s12 + SSIM_C2);
                        const float den = (mu1s + mu2s + SSIM_C1) * (s1 + s2 + SSIM_C2);
                        lsum += num / den;
                    }
                }
                __syncthreads();
            }
        }
    }

    // deterministic block reduction
    red[tid] = lsum;
    __syncthreads();
    for (int off = 256; off > 0; off >>= 1) {
        if (tid < off) red[tid] += red[tid + off];
        __syncthreads();
    }
    if (tid == 0)
        partials[(blockIdx.z * gridDim.y + blockIdx.y) * gridDim.x + blockIdx.x] = red[0];
}

__global__ __launch_bounds__(256) void k_final(
    const float* __restrict__ partials, int n, float scale, float* __restrict__ out)
{
    __shared__ float red[256];
    float s = 0.f;
    for (int i = threadIdx.x; i < n; i += 256) s += partials[i];
    red[threadIdx.x] = s;
    __syncthreads();
    for (int off = 128; off > 0; off >>= 1) {
        if (threadIdx.x < off) red[threadIdx.x] += red[threadIdx.x + off];
        __syncthreads();
    }
    if (threadIdx.x == 0) out[0] = red[0] * scale;
}

extern "C" void kernel_launch(void* const* d_in, const int* in_sizes, int n_in,
                              void* d_out, int out_size, void* d_ws, size_t ws_size,
                              hipStream_t stream)
{
    const float* img1 = (const float*)d_in[0];
    const float* img2 = (const float*)d_in[1];
    float* out = (float*)d_out;
    float* partials = (float*)d_ws;

    Gw gw;
    {
        double gs[7], sum = 0.0;
        for (int i = 0; i < 7; ++i) { double x = i - 3; gs[i] = exp(-x * x / 4.5); sum += gs[i]; }
        for (int i = 0; i < 7; ++i) gw.g[i] = (float)(gs[i] / sum);
    }

    dim3 grid(8, 8, NB * 2);   // 256 blocks, one per CU
    k_fused<<<grid, dim3(512), 0, stream>>>(img1, img2, gw, partials);
    k_final<<<dim3(1), dim3(256), 0, stream>>>(
        partials, 8 * 8 * NB * 2, (float)(1.0 / 20971520.0), out);
}